// Round 1
// baseline (442.979 us; speedup 1.0000x reference)
//
#include <hip/hip_runtime.h>
#include <cstdint>
#include <cstddef>

using short8  = __attribute__((ext_vector_type(8))) short;
using floatx4 = __attribute__((ext_vector_type(4))) float;

#define DEV __device__ __forceinline__

DEV float u2f(unsigned short u){
  union { unsigned int i; float f; } c; c.i = ((unsigned int)u) << 16; return c.f;
}
DEV unsigned short f2u(float f){
  union { float f; unsigned int i; } c; c.f = f;
  unsigned int i = c.i;
  i += 0x7fffu + ((i >> 16) & 1u);   // RNE to bf16 (finite values only here)
  return (unsigned short)(i >> 16);
}
DEV float sigmoidf_(float x){ return 1.0f / (1.0f + __expf(-x)); }
DEV float siluf_(float x){ return x / (1.0f + __expf(-x)); }

// problem-fixed sizes
// T=2048 S=2048 B=4 E=1024 Z=128
constexpr float SCALING = 0.088388347648318447f; // 128^-0.5

// ---------------------------------------------------------------- casts
__global__ __launch_bounds__(256) void cast_f32_bf16(
    const float* __restrict__ in, unsigned short* __restrict__ out, int n)
{
  const int i = (blockIdx.x * 256 + threadIdx.x) * 4;
  if (i >= n) return;
  const float4 v = *(const float4*)(in + i);
  ushort4 o;
  o.x = f2u(v.x); o.y = f2u(v.y); o.z = f2u(v.z); o.w = f2u(v.w);
  *(ushort4*)(out + i) = o;
}

// ---------------------------------------------------------------- softmax
// one block per row of (B*T) rows, S=2048 fp32 logits; writes bf16 probs
// in-place into the same row (row stride stays 2048 floats = 4096 bf16).
__global__ __launch_bounds__(256) void softmax_rows(float* __restrict__ logits)
{
  const long long rb = blockIdx.x;
  float* row = logits + rb * 2048;
  unsigned short* prow = (unsigned short*)logits + rb * 4096;
  const int tid = threadIdx.x;
  const int lane = tid & 63, wv = tid >> 6;

  const float4 a = *(const float4*)(row + tid * 4);
  const float4 b = *(const float4*)(row + 1024 + tid * 4);

  float mx = fmaxf(fmaxf(fmaxf(a.x,a.y),fmaxf(a.z,a.w)),
                   fmaxf(fmaxf(b.x,b.y),fmaxf(b.z,b.w)));
  #pragma unroll
  for (int m = 32; m >= 1; m >>= 1) mx = fmaxf(mx, __shfl_xor(mx, m));
  __shared__ float red[4];
  if (lane == 0) red[wv] = mx;
  __syncthreads();
  mx = fmaxf(fmaxf(red[0], red[1]), fmaxf(red[2], red[3]));

  float e[8];
  e[0]=__expf(a.x-mx); e[1]=__expf(a.y-mx); e[2]=__expf(a.z-mx); e[3]=__expf(a.w-mx);
  e[4]=__expf(b.x-mx); e[5]=__expf(b.y-mx); e[6]=__expf(b.z-mx); e[7]=__expf(b.w-mx);
  float sm = 0.f;
  #pragma unroll
  for (int i = 0; i < 8; i++) sm += e[i];
  #pragma unroll
  for (int m = 32; m >= 1; m >>= 1) sm += __shfl_xor(sm, m);
  __syncthreads();                 // red[] reuse
  if (lane == 0) red[wv] = sm;
  __syncthreads();
  const float inv = 1.0f / (red[0] + red[1] + red[2] + red[3]);

  ushort4 o0, o1;
  o0.x=f2u(e[0]*inv); o0.y=f2u(e[1]*inv); o0.z=f2u(e[2]*inv); o0.w=f2u(e[3]*inv);
  o1.x=f2u(e[4]*inv); o1.y=f2u(e[5]*inv); o1.z=f2u(e[6]*inv); o1.w=f2u(e[7]*inv);
  *(ushort4*)(prow + tid * 4) = o0;
  *(ushort4*)(prow + 1024 + tid * 4) = o1;
}

// ---------------------------------------------------------------- GEMM-BT
// C[M,N] = A[M,K] * B[N,K]^T  (both row-major over K), bf16 inputs, fp32 acc.
// 128x128 block tile, BK=64, 256 threads = 4 waves in 2x2, each wave 64x64
// via 4x4 grid of 16x16x32 MFMAs.
// EPI: 0 = Wq proj (u/r/q split), 1 = k proj, 2 = v proj -> v^T scatter,
//      3 = qk logits (fp32, batched), 4 = PV -> hr = h*r (bf16),
//      5 = Wh proj -> out = q + u*(tanh(.)-q)  (fp32)
template<int EPI>
__global__ __launch_bounds__(256, 2)
void gemm_bt(const unsigned short* __restrict__ A, long long bsA, int lda,
             const unsigned short* __restrict__ Bm, long long bsB, int ldb,
             int K,
             const float* __restrict__ bias,
             const float* __restrict__ gam,
             const float* __restrict__ bet,
             float* __restrict__ f0,
             unsigned short* __restrict__ b0,
             unsigned short* __restrict__ b1,
             const unsigned short* __restrict__ rmul,
             const float* __restrict__ qin,
             const float* __restrict__ uin)
{
  __shared__ __align__(16) unsigned short As[128][72];  // +8 pad: 2-way banks (free)
  __shared__ __align__(16) unsigned short Bs[128][72];

  const int tid = threadIdx.x;
  const int bm = blockIdx.x, bn = blockIdx.y, bz = blockIdx.z;
  const unsigned short* Ag = A  + (long long)bz * bsA;
  const unsigned short* Bg = Bm + (long long)bz * bsB;
  const int row0 = bm * 128;
  const int col0 = bn * 128;

  const int lane = tid & 63;
  const int wv   = tid >> 6;
  const int wm   = (wv & 1) * 64;
  const int wn   = (wv >> 1) * 64;
  const int lr   = lane & 15;   // fragment m/n index
  const int lq   = lane >> 4;   // quad: k = lq*8.., C row = lq*4+reg

  floatx4 acc[4][4];
  const floatx4 zero = {0.f, 0.f, 0.f, 0.f};
  #pragma unroll
  for (int i = 0; i < 4; i++)
    #pragma unroll
    for (int j = 0; j < 4; j++) acc[i][j] = zero;

  for (int kt = 0; kt < K; kt += 64) {
    #pragma unroll
    for (int i = 0; i < 4; i++) {            // 1024 chunks of 8 bf16 per tile
      const int c  = tid + i * 256;
      const int rr = c >> 3;
      const int kc = (c & 7) << 3;
      *(short8*)(&As[rr][kc]) = *(const short8*)(Ag + (long long)(row0 + rr) * lda + kt + kc);
      *(short8*)(&Bs[rr][kc]) = *(const short8*)(Bg + (long long)(col0 + rr) * ldb + kt + kc);
    }
    __syncthreads();
    #pragma unroll
    for (int ks = 0; ks < 64; ks += 32) {
      short8 af[4], bfv[4];
      #pragma unroll
      for (int i = 0; i < 4; i++) af[i]  = *(const short8*)(&As[wm + i*16 + lr][ks + lq*8]);
      #pragma unroll
      for (int i = 0; i < 4; i++) bfv[i] = *(const short8*)(&Bs[wn + i*16 + lr][ks + lq*8]);
      #pragma unroll
      for (int mi = 0; mi < 4; mi++)
        #pragma unroll
        for (int ni = 0; ni < 4; ni++)
          acc[mi][ni] = __builtin_amdgcn_mfma_f32_16x16x32_bf16(af[mi], bfv[ni], acc[mi][ni], 0, 0, 0);
    }
    __syncthreads();
  }

  #pragma unroll
  for (int mi = 0; mi < 4; mi++) {
    #pragma unroll
    for (int ni = 0; ni < 4; ni++) {
      #pragma unroll
      for (int r = 0; r < 4; r++) {
        const int gm = row0 + wm + mi * 16 + lq * 4 + r;
        const int gn = col0 + wn + ni * 16 + lr;
        float v = acc[mi][ni][r];
        if constexpr (EPI == 0) {
          v += bias[gn];
          if (gn < 1024) {
            f0[(long long)gm * 1024 + gn] = sigmoidf_(v);               // u (fp32)
          } else if (gn < 2048) {
            b0[(long long)gm * 1024 + (gn - 1024)] = f2u(siluf_(v));    // r (bf16)
          } else {
            const int z = gn - 2048;
            b1[(long long)gm * 128 + z] = f2u(siluf_(v) * gam[z] + bet[z]); // q
          }
        } else if constexpr (EPI == 1) {
          v += bias[gn];
          b0[(long long)gm * 128 + gn] = f2u(siluf_(v) * gam[gn] + bet[gn]); // k
        } else if constexpr (EPI == 2) {
          v += bias[gn];
          const int s = gm >> 2, bb = gm & 3;                            // m = s*B+b
          b0[((long long)bb * 1024 + gn) * 2048 + s] = f2u(siluf_(v));   // v^T[b][e][s]
        } else if constexpr (EPI == 3) {
          f0[(long long)bz * 2048 * 2048 + (long long)gm * 2048 + gn] = v * SCALING;
        } else if constexpr (EPI == 4) {
          const long long idx = ((long long)gm * 4 + bz) * 1024 + gn;    // (t,b,e)
          b0[idx] = f2u(v * u2f(rmul[idx]));                             // hr = h*r
        } else { // EPI == 5
          const long long idx = (long long)gm * 1024 + gn;
          const float tv = tanhf(v + bias[gn]);
          const float qv = qin[idx];
          f0[idx] = qv + uin[idx] * (tv - qv);                           // final out
        }
      }
    }
  }
}

// ---------------------------------------------------------------- launch
extern "C" void kernel_launch(void* const* d_in, const int* in_sizes, int n_in,
                              void* d_out, int out_size, void* d_ws, size_t ws_size,
                              hipStream_t stream)
{
  (void)in_sizes; (void)n_in; (void)out_size; (void)ws_size;
  const float* query = (const float*)d_in[0];
  const float* key   = (const float*)d_in[1];
  const float* Wq    = (const float*)d_in[2];
  const float* bq    = (const float*)d_in[3];
  const float* Wk    = (const float*)d_in[4];
  const float* bk    = (const float*)d_in[5];
  const float* Wv    = (const float*)d_in[6];
  const float* bv    = (const float*)d_in[7];
  const float* Wh    = (const float*)d_in[8];
  const float* bh    = (const float*)d_in[9];
  const float* gamma = (const float*)d_in[10];
  const float* beta  = (const float*)d_in[11];
  float* out = (float*)d_out;

  char* p = (char*)d_ws;
  auto take = [&](size_t bytes) -> char* {
    char* r = p; p += (bytes + 255) & ~(size_t)255; return r;
  };
  unsigned short* qbf = (unsigned short*)take(8192ULL * 1024 * 2); // query bf16
  unsigned short* kbf = (unsigned short*)take(8192ULL * 1024 * 2); // key bf16
  unsigned short* Wqb = (unsigned short*)take(2176ULL * 1024 * 2);
  unsigned short* Wkb = (unsigned short*)take(128ULL  * 1024 * 2);
  unsigned short* Wvb = (unsigned short*)take(1024ULL * 1024 * 2);
  unsigned short* Whb = (unsigned short*)take(1024ULL * 1024 * 2);
  float*          u_  = (float*)take(8192ULL * 1024 * 4);          // u gate fp32
  unsigned short* rbf = (unsigned short*)take(8192ULL * 1024 * 2); // r bf16
  unsigned short* qpj = (unsigned short*)take(8192ULL * 128 * 2);  // q (T,B,Z)
  unsigned short* kpj = (unsigned short*)take(8192ULL * 128 * 2);  // k (S,B,Z)
  unsigned short* vT  = (unsigned short*)take(4ULL * 1024 * 2048 * 2); // v^T (B,E,S)
  float*          lg  = (float*)take(4ULL * 2048 * 2048 * 4);      // logits / P
  unsigned short* hrb = (unsigned short*)take(8192ULL * 1024 * 2); // h*r bf16

  dim3 blk(256);
  cast_f32_bf16<<<8192, blk, 0, stream>>>(query, qbf, 8192 * 1024);
  cast_f32_bf16<<<8192, blk, 0, stream>>>(key,   kbf, 8192 * 1024);
  cast_f32_bf16<<<2176, blk, 0, stream>>>(Wq,    Wqb, 2176 * 1024);
  cast_f32_bf16<<<128,  blk, 0, stream>>>(Wk,    Wkb, 128 * 1024);
  cast_f32_bf16<<<1024, blk, 0, stream>>>(Wv,    Wvb, 1024 * 1024);
  cast_f32_bf16<<<1024, blk, 0, stream>>>(Wh,    Whb, 1024 * 1024);

  // base = query @ Wq^T + bq -> u (sigmoid), r (silu), q (silu*g0+b0)
  gemm_bt<0><<<dim3(64, 17, 1), blk, 0, stream>>>(qbf, 0, 1024, Wqb, 0, 1024, 1024,
      bq, gamma, beta, u_, rbf, qpj, nullptr, nullptr, nullptr);
  // k = silu(key @ Wk^T + bk)*g1+b1
  gemm_bt<1><<<dim3(64, 1, 1), blk, 0, stream>>>(kbf, 0, 1024, Wkb, 0, 1024, 1024,
      bk, gamma + 128, beta + 128, nullptr, kpj, nullptr, nullptr, nullptr, nullptr);
  // v = silu(key @ Wv^T + bv), stored transposed (B,E,S)
  gemm_bt<2><<<dim3(64, 8, 1), blk, 0, stream>>>(kbf, 0, 1024, Wvb, 0, 1024, 1024,
      bv, nullptr, nullptr, nullptr, vT, nullptr, nullptr, nullptr, nullptr);
  // logits[b,t,s] = scaling * q_b @ k_b^T   (batched over b via blockIdx.z)
  gemm_bt<3><<<dim3(16, 16, 4), blk, 0, stream>>>(qpj, 128, 512, kpj, 128, 512, 128,
      nullptr, nullptr, nullptr, lg, nullptr, nullptr, nullptr, nullptr, nullptr);
  // softmax rows -> bf16 P in-place (row stride 4096 bf16)
  softmax_rows<<<8192, blk, 0, stream>>>(lg);
  // hr[t,b,e] = (P_b @ vT_b^T) * r
  gemm_bt<4><<<dim3(16, 8, 4), blk, 0, stream>>>((unsigned short*)lg, 2048LL * 4096, 4096,
      vT, 1024LL * 2048, 2048, 2048,
      nullptr, nullptr, nullptr, nullptr, hrb, nullptr, rbf, nullptr, nullptr);
  // out = query + u * (tanh(hr @ Wh^T + bh) - query)
  gemm_bt<5><<<dim3(64, 8, 1), blk, 0, stream>>>(hrb, 0, 1024, Whb, 0, 1024, 1024,
      bh, nullptr, nullptr, out, nullptr, nullptr, nullptr, query, u_);
}

// Round 2
// 395.382 us; speedup vs baseline: 1.1204x; 1.1204x over previous
//
#include <hip/hip_runtime.h>
#include <cstdint>
#include <cstddef>

using short8  = __attribute__((ext_vector_type(8))) short;
using floatx4 = __attribute__((ext_vector_type(4))) float;

#define DEV __device__ __forceinline__

DEV float u2f(unsigned short u){
  union { unsigned int i; float f; } c; c.i = ((unsigned int)u) << 16; return c.f;
}
DEV unsigned short f2u(float f){
  union { float f; unsigned int i; } c; c.f = f;
  unsigned int i = c.i;
  i += 0x7fffu + ((i >> 16) & 1u);   // RNE to bf16 (finite values only here)
  return (unsigned short)(i >> 16);
}
DEV float sigmoidf_(float x){ return 1.0f / (1.0f + __expf(-x)); }
DEV float siluf_(float x){ return x / (1.0f + __expf(-x)); }

// async global->LDS, 16 B per lane; LDS dest must be wave-uniform base + lane*16
#define ASYNC_LD16(g, l) __builtin_amdgcn_global_load_lds( \
    (const __attribute__((address_space(1))) unsigned int*)(g), \
    (__attribute__((address_space(3))) unsigned int*)(l), 16, 0, 0)

// problem-fixed sizes: T=2048 S=2048 B=4 E=1024 Z=128
constexpr float SCALING = 0.088388347648318447f; // 128^-0.5

// ---------------------------------------------------------------- casts
__global__ __launch_bounds__(256) void cast_f32_bf16(
    const float* __restrict__ in, unsigned short* __restrict__ out, int n)
{
  const int i = (blockIdx.x * 256 + threadIdx.x) * 4;
  if (i >= n) return;
  const float4 v = *(const float4*)(in + i);
  ushort4 o;
  o.x = f2u(v.x); o.y = f2u(v.y); o.z = f2u(v.z); o.w = f2u(v.w);
  *(ushort4*)(out + i) = o;
}

// ---------------------------------------------------------------- softmax
// one block per row of (B*T) rows, S=2048 fp32 logits; writes bf16 probs
// in-place into the same row (row stride stays 2048 floats = 4096 bf16).
__global__ __launch_bounds__(256) void softmax_rows(float* __restrict__ logits)
{
  const long long rb = blockIdx.x;
  float* row = logits + rb * 2048;
  unsigned short* prow = (unsigned short*)logits + rb * 4096;
  const int tid = threadIdx.x;
  const int lane = tid & 63, wv = tid >> 6;

  const float4 a = *(const float4*)(row + tid * 4);
  const float4 b = *(const float4*)(row + 1024 + tid * 4);

  float mx = fmaxf(fmaxf(fmaxf(a.x,a.y),fmaxf(a.z,a.w)),
                   fmaxf(fmaxf(b.x,b.y),fmaxf(b.z,b.w)));
  #pragma unroll
  for (int m = 32; m >= 1; m >>= 1) mx = fmaxf(mx, __shfl_xor(mx, m));
  __shared__ float red[4];
  if (lane == 0) red[wv] = mx;
  __syncthreads();
  mx = fmaxf(fmaxf(red[0], red[1]), fmaxf(red[2], red[3]));

  float e[8];
  e[0]=__expf(a.x-mx); e[1]=__expf(a.y-mx); e[2]=__expf(a.z-mx); e[3]=__expf(a.w-mx);
  e[4]=__expf(b.x-mx); e[5]=__expf(b.y-mx); e[6]=__expf(b.z-mx); e[7]=__expf(b.w-mx);
  float sm = 0.f;
  #pragma unroll
  for (int i = 0; i < 8; i++) sm += e[i];
  #pragma unroll
  for (int m = 32; m >= 1; m >>= 1) sm += __shfl_xor(sm, m);
  __syncthreads();                 // red[] reuse
  if (lane == 0) red[wv] = sm;
  __syncthreads();
  const float inv = 1.0f / (red[0] + red[1] + red[2] + red[3]);

  ushort4 o0, o1;
  o0.x=f2u(e[0]*inv); o0.y=f2u(e[1]*inv); o0.z=f2u(e[2]*inv); o0.w=f2u(e[3]*inv);
  o1.x=f2u(e[4]*inv); o1.y=f2u(e[5]*inv); o1.z=f2u(e[6]*inv); o1.w=f2u(e[7]*inv);
  *(ushort4*)(prow + tid * 4) = o0;
  *(ushort4*)(prow + 1024 + tid * 4) = o1;
}

// ---------------------------------------------------------------- GEMM-BT
// C[M,N] = A[M,K] * B[N,K]^T, bf16 in, fp32 acc. 128x128 tile, BK=64,
// 256 threads = 4 waves (2x2), each wave 64x64 via 4x4 of 16x16x32 MFMA.
// Staging: global_load_lds width=16 (async DMA, no VGPR round-trip).
// LDS layout: unpadded 128x64 with XOR-swizzle — row r, slot s holds global
// col-chunk s^(r&7); read side covers all 32 banks (2 lanes/bank = free).
template<int EPI>
__global__ __launch_bounds__(256, 2)
void gemm_bt(const unsigned short* __restrict__ A, long long bsA, int lda,
             const unsigned short* __restrict__ Bm, long long bsB, int ldb,
             int K,
             const float* __restrict__ bias,
             const float* __restrict__ gam,
             const float* __restrict__ bet,
             float* __restrict__ f0,
             unsigned short* __restrict__ b0,
             unsigned short* __restrict__ b1,
             const unsigned short* __restrict__ rmul,
             const float* __restrict__ qin,
             const float* __restrict__ uin)
{
  __shared__ __align__(16) unsigned short As[128][64];
  __shared__ __align__(16) unsigned short Bs[128][64];

  const int tid = threadIdx.x;
  const int bm = blockIdx.x, bn = blockIdx.y, bz = blockIdx.z;
  const unsigned short* Ag = A  + (long long)bz * bsA;
  const unsigned short* Bg = Bm + (long long)bz * bsB;
  const int row0 = bm * 128;
  const int col0 = bn * 128;

  const int lane = tid & 63;
  const int wv   = tid >> 6;
  const int wm   = (wv & 1) * 64;
  const int wn   = (wv >> 1) * 64;
  const int lr   = lane & 15;   // fragment m/n index
  const int lq   = lane >> 4;   // quad: k = lq*8.., C row = lq*4+reg
  const int r7   = lr & 7;      // read-side swizzle key

  // staging addresses (hoisted; kt added in-loop). chunk c = tid + i*256:
  // row rr=c>>3, LDS slot c&7 holds global chunk gc=(c&7)^(rr&7).
  const unsigned short* gA[4]; const unsigned short* gB[4];
  unsigned short* lA[4]; unsigned short* lB[4];
  #pragma unroll
  for (int i = 0; i < 4; i++) {
    const int c  = tid + i * 256;
    const int rr = c >> 3;
    const int gc = (c & 7) ^ (rr & 7);
    gA[i] = Ag + (long long)(row0 + rr) * lda + gc * 8;
    gB[i] = Bg + (long long)(col0 + rr) * ldb + gc * 8;
    lA[i] = &As[0][0] + c * 8;
    lB[i] = &Bs[0][0] + c * 8;
  }

  floatx4 acc[4][4];
  const floatx4 zero = {0.f, 0.f, 0.f, 0.f};
  #pragma unroll
  for (int i = 0; i < 4; i++)
    #pragma unroll
    for (int j = 0; j < 4; j++) acc[i][j] = zero;

  for (int kt = 0; kt < K; kt += 64) {
    #pragma unroll
    for (int i = 0; i < 4; i++) {
      ASYNC_LD16(gA[i] + kt, lA[i]);
      ASYNC_LD16(gB[i] + kt, lB[i]);
    }
    __syncthreads();               // waits vmcnt(0): LDS tiles complete
    #pragma unroll
    for (int ks = 0; ks < 64; ks += 32) {
      const int k8 = ks >> 3;
      short8 af[4], bfv[4];
      #pragma unroll
      for (int i = 0; i < 4; i++) {
        const int sc = (lq + k8) ^ r7;
        af[i]  = *(const short8*)(&As[wm + i*16 + lr][sc * 8]);
        bfv[i] = *(const short8*)(&Bs[wn + i*16 + lr][sc * 8]);
      }
      #pragma unroll
      for (int mi = 0; mi < 4; mi++)
        #pragma unroll
        for (int ni = 0; ni < 4; ni++)
          acc[mi][ni] = __builtin_amdgcn_mfma_f32_16x16x32_bf16(af[mi], bfv[ni], acc[mi][ni], 0, 0, 0);
    }
    __syncthreads();               // all reads done before next tile DMA
  }

  #pragma unroll
  for (int mi = 0; mi < 4; mi++) {
    #pragma unroll
    for (int ni = 0; ni < 4; ni++) {
      #pragma unroll
      for (int r = 0; r < 4; r++) {
        const int gm = row0 + wm + mi * 16 + lq * 4 + r;
        const int gn = col0 + wn + ni * 16 + lr;
        float v = acc[mi][ni][r];
        if constexpr (EPI == 0) {
          v += bias[gn];
          if (gn < 1024) {
            f0[(long long)gm * 1024 + gn] = sigmoidf_(v);               // u (fp32)
          } else if (gn < 2048) {
            b0[(long long)gm * 1024 + (gn - 1024)] = f2u(siluf_(v));    // r (bf16)
          } else {
            const int z = gn - 2048;
            b1[(long long)gm * 128 + z] = f2u(siluf_(v) * gam[z] + bet[z]); // q
          }
        } else if constexpr (EPI == 1) {
          v += bias[gn];
          b0[(long long)gm * 128 + gn] = f2u(siluf_(v) * gam[gn] + bet[gn]); // k
        } else if constexpr (EPI == 2) {
          v += bias[gn];
          const int s = gm >> 2, bb = gm & 3;                            // m = s*B+b
          b0[((long long)bb * 1024 + gn) * 2048 + s] = f2u(siluf_(v));   // v^T[b][e][s]
        } else if constexpr (EPI == 3) {
          f0[(long long)bz * 2048 * 2048 + (long long)gm * 2048 + gn] = v * SCALING;
        } else if constexpr (EPI == 4) {
          const long long idx = ((long long)gm * 4 + bz) * 1024 + gn;    // (t,b,e)
          b0[idx] = f2u(v * u2f(rmul[idx]));                             // hr = h*r
        } else { // EPI == 5
          const long long idx = (long long)gm * 1024 + gn;
          const float tv = tanhf(v + bias[gn]);
          const float qv = qin[idx];
          f0[idx] = qv + uin[idx] * (tv - qv);                           // final out
        }
      }
    }
  }
}

// ---------------------------------------------------------------- launch
extern "C" void kernel_launch(void* const* d_in, const int* in_sizes, int n_in,
                              void* d_out, int out_size, void* d_ws, size_t ws_size,
                              hipStream_t stream)
{
  (void)in_sizes; (void)n_in; (void)out_size; (void)ws_size;
  const float* query = (const float*)d_in[0];
  const float* key   = (const float*)d_in[1];
  const float* Wq    = (const float*)d_in[2];
  const float* bq    = (const float*)d_in[3];
  const float* Wk    = (const float*)d_in[4];
  const float* bk    = (const float*)d_in[5];
  const float* Wv    = (const float*)d_in[6];
  const float* bv    = (const float*)d_in[7];
  const float* Wh    = (const float*)d_in[8];
  const float* bh    = (const float*)d_in[9];
  const float* gamma = (const float*)d_in[10];
  const float* beta  = (const float*)d_in[11];
  float* out = (float*)d_out;

  char* p = (char*)d_ws;
  auto take = [&](size_t bytes) -> char* {
    char* r = p; p += (bytes + 255) & ~(size_t)255; return r;
  };
  unsigned short* qbf = (unsigned short*)take(8192ULL * 1024 * 2); // query bf16
  unsigned short* kbf = (unsigned short*)take(8192ULL * 1024 * 2); // key bf16
  unsigned short* Wqb = (unsigned short*)take(2176ULL * 1024 * 2);
  unsigned short* Wkb = (unsigned short*)take(128ULL  * 1024 * 2);
  unsigned short* Wvb = (unsigned short*)take(1024ULL * 1024 * 2);
  unsigned short* Whb = (unsigned short*)take(1024ULL * 1024 * 2);
  float*          u_  = (float*)take(8192ULL * 1024 * 4);          // u gate fp32
  unsigned short* rbf = (unsigned short*)take(8192ULL * 1024 * 2); // r bf16
  unsigned short* qpj = (unsigned short*)take(8192ULL * 128 * 2);  // q (T,B,Z)
  unsigned short* kpj = (unsigned short*)take(8192ULL * 128 * 2);  // k (S,B,Z)
  unsigned short* vT  = (unsigned short*)take(4ULL * 1024 * 2048 * 2); // v^T (B,E,S)
  float*          lg  = (float*)take(4ULL * 2048 * 2048 * 4);      // logits / P
  unsigned short* hrb = (unsigned short*)take(8192ULL * 1024 * 2); // h*r bf16

  dim3 blk(256);
  cast_f32_bf16<<<8192, blk, 0, stream>>>(query, qbf, 8192 * 1024);
  cast_f32_bf16<<<8192, blk, 0, stream>>>(key,   kbf, 8192 * 1024);
  cast_f32_bf16<<<2176, blk, 0, stream>>>(Wq,    Wqb, 2176 * 1024);
  cast_f32_bf16<<<128,  blk, 0, stream>>>(Wk,    Wkb, 128 * 1024);
  cast_f32_bf16<<<1024, blk, 0, stream>>>(Wv,    Wvb, 1024 * 1024);
  cast_f32_bf16<<<1024, blk, 0, stream>>>(Wh,    Whb, 1024 * 1024);

  // base = query @ Wq^T + bq -> u (sigmoid), r (silu), q (silu*g0+b0)
  gemm_bt<0><<<dim3(64, 17, 1), blk, 0, stream>>>(qbf, 0, 1024, Wqb, 0, 1024, 1024,
      bq, gamma, beta, u_, rbf, qpj, nullptr, nullptr, nullptr);
  // k = silu(key @ Wk^T + bk)*g1+b1
  gemm_bt<1><<<dim3(64, 1, 1), blk, 0, stream>>>(kbf, 0, 1024, Wkb, 0, 1024, 1024,
      bk, gamma + 128, beta + 128, nullptr, kpj, nullptr, nullptr, nullptr, nullptr);
  // v = silu(key @ Wv^T + bv), stored transposed (B,E,S)
  gemm_bt<2><<<dim3(64, 8, 1), blk, 0, stream>>>(kbf, 0, 1024, Wvb, 0, 1024, 1024,
      bv, nullptr, nullptr, nullptr, vT, nullptr, nullptr, nullptr, nullptr);
  // logits[b,t,s] = scaling * q_b @ k_b^T   (batched over b via blockIdx.z)
  gemm_bt<3><<<dim3(16, 16, 4), blk, 0, stream>>>(qpj, 128, 512, kpj, 128, 512, 128,
      nullptr, nullptr, nullptr, lg, nullptr, nullptr, nullptr, nullptr, nullptr);
  // softmax rows -> bf16 P in-place (row stride 4096 bf16)
  softmax_rows<<<8192, blk, 0, stream>>>(lg);
  // hr[t,b,e] = (P_b @ vT_b^T) * r
  gemm_bt<4><<<dim3(16, 8, 4), blk, 0, stream>>>((unsigned short*)lg, 2048LL * 4096, 4096,
      vT, 1024LL * 2048, 2048, 2048,
      nullptr, nullptr, nullptr, nullptr, hrb, nullptr, rbf, nullptr, nullptr);
  // out = query + u * (tanh(hr @ Wh^T + bh) - query)
  gemm_bt<5><<<dim3(64, 8, 1), blk, 0, stream>>>(hrb, 0, 1024, Whb, 0, 1024, 1024,
      bh, nullptr, nullptr, out, nullptr, nullptr, nullptr, query, u_);
}